// Round 3
// baseline (663.886 us; speedup 1.0000x reference)
//
#include <hip/hip_runtime.h>

#define T_N 1024
#define H_N 128
#define CH   64
#define NCH (T_N / CH)   // 16 chunks
#define WPAD 136         // wT row stride (shorts): +8 keeps 16B align, breaks bank conflicts

typedef __attribute__((ext_vector_type(8))) short bf16x8;
typedef __attribute__((ext_vector_type(4))) float f32x4;

__device__ __forceinline__ short f2bf_rne(float f) {
    union { float f; unsigned int i; } v; v.f = f;
    unsigned int r = v.i + 0x7FFFu + ((v.i >> 16) & 1u);
    return (short)(r >> 16);
}
__device__ __forceinline__ float tanh_fast(float x) {
    return 1.0f - 2.0f / (__expf(2.0f * x) + 1.0f);   // exact at +-inf, no NaN for finite x
}

// One block per batch row; 256 threads = 4 waves.
// Per 64-step chunk: MFMA (bf16-cast) computes proj into LDS (fp32, +bias);
// then the serial recurrence runs in exact fp32 with a 2-way K-split.
__global__ __launch_bounds__(256, 1) void k_fused(const float* __restrict__ x,
                                                  const float* __restrict__ w,
                                                  const float* __restrict__ wst,
                                                  const float* __restrict__ bias,
                                                  float* __restrict__ out) {
    __shared__ float pbuf[CH][H_N];      // 32 KB proj chunk (fp32, bias included)
    __shared__ short wT[H_N * WPAD];     // 34 KB bf16 w, [n][k] layout, padded
    __shared__ float sbuf[2][H_N];       // fp32 state double buffer
    __shared__ float part[256];          // K-split partials

    const int tid  = threadIdx.x;
    const int wv   = tid >> 6;           // wave id: GEMM row-tile
    const int lane = tid & 63;
    const int lr   = lane & 15;
    const int q    = lane >> 4;
    const int h    = tid & 127;          // recurrence output column
    const int half = tid >> 7;           // K-split half
    const int r    = blockIdx.x;         // batch row

    // ---- one-time: w [k][n] fp32 -> wT [n][k] bf16 in LDS ----
    for (int e = tid; e < H_N * H_N; e += 256) {
        int k = e >> 7, n = e & 127;
        wT[n * WPAD + k] = f2bf_rne(w[e]);
    }

    // W_state half-column, exact fp32: wcol[k] = wst[half*64+k][h]
    float wcol[64];
    #pragma unroll
    for (int k = 0; k < 64; ++k) wcol[k] = wst[(half * 64 + k) * H_N + h];

    float bv[8];
    #pragma unroll
    for (int nt = 0; nt < 8; ++nt) bv[nt] = bias[nt * 16 + lr];

    const float* xrow = x + (size_t)r * T_N * H_N;   // D == H == 128

    // fp32 staging for chunk 0 A-fragments: lane holds x[row=wv*16+lr][k=ks*32+q*8..+7]
    float4 st[8];
    {
        const float4* xp = reinterpret_cast<const float4*>(xrow + (size_t)(wv * 16 + lr) * H_N);
        #pragma unroll
        for (int ks = 0; ks < 4; ++ks) {
            st[ks * 2 + 0] = xp[ks * 8 + q * 2 + 0];
            st[ks * 2 + 1] = xp[ks * 8 + q * 2 + 1];
        }
    }

    __syncthreads();   // wT ready

    int par = 0;
    #pragma unroll 1
    for (int c = 0; c < NCH; ++c) {
        __syncthreads();   // previous chunk's recurrence done with pbuf

        // cvt current staging -> bf16 A-fragments
        bf16x8 a[4];
        #pragma unroll
        for (int ks = 0; ks < 4; ++ks) {
            bf16x8 f;
            #pragma unroll
            for (int j = 0; j < 4; ++j) {
                f[j]     = f2bf_rne(((const float*)&st[ks * 2 + 0])[j]);
                f[j + 4] = f2bf_rne(((const float*)&st[ks * 2 + 1])[j]);
            }
            a[ks] = f;
        }

        // prefetch fp32 staging for next chunk (completes during recurrence)
        {
            int cn = (c + 1 < NCH) ? c + 1 : c;
            const float4* xp = reinterpret_cast<const float4*>(
                xrow + (size_t)(cn * CH + wv * 16 + lr) * H_N);
            #pragma unroll
            for (int ks = 0; ks < 4; ++ks) {
                st[ks * 2 + 0] = xp[ks * 8 + q * 2 + 0];
                st[ks * 2 + 1] = xp[ks * 8 + q * 2 + 1];
            }
        }

        // GEMM: wave wv computes proj rows [c*CH+wv*16 .. +15], all 128 cols
        #pragma unroll
        for (int nt = 0; nt < 8; ++nt) {
            f32x4 acc = (f32x4){0.f, 0.f, 0.f, 0.f};
            #pragma unroll
            for (int ks = 0; ks < 4; ++ks) {
                bf16x8 bf = *reinterpret_cast<const bf16x8*>(
                    &wT[(nt * 16 + lr) * WPAD + ks * 32 + q * 8]);
                acc = __builtin_amdgcn_mfma_f32_16x16x32_bf16(a[ks], bf, acc, 0, 0, 0);
            }
            // D layout: row(m)=q*4+i, col(n)=nt*16+lr
            #pragma unroll
            for (int i = 0; i < 4; ++i)
                pbuf[wv * 16 + q * 4 + i][nt * 16 + lr] = acc[i] + bv[nt];
        }
        __syncthreads();   // pbuf ready

        int tstart = 0;
        if (c == 0) {
            if (tid < 128) sbuf[0][h] = tanh_fast(pbuf[0][h]);   // state0: no recurrent term
            __syncthreads();
            tstart = 1;
            par = 0;
        }

        #pragma unroll 1
        for (int t = tstart; t < CH; ++t) {
            const float4* s4 = reinterpret_cast<const float4*>(&sbuf[par][half * 64]);
            float a0 = 0.f, a1 = 0.f, a2 = 0.f, a3 = 0.f;
            #pragma unroll
            for (int k4 = 0; k4 < 16; ++k4) {
                float4 sv = s4[k4];   // wave-uniform broadcast read
                a0 += sv.x * wcol[k4 * 4 + 0];
                a1 += sv.y * wcol[k4 * 4 + 1];
                a2 += sv.z * wcol[k4 * 4 + 2];
                a3 += sv.w * wcol[k4 * 4 + 3];
            }
            float ps = (a0 + a1) + (a2 + a3);
            part[tid] = ps;
            __syncthreads();
            if (tid < 128) {   // wave-uniform branch (waves 0,1)
                float z = pbuf[t][h] + ps + part[h + 128];
                sbuf[par ^ 1][h] = tanh_fast(z);
            }
            __syncthreads();
            par ^= 1;
        }
    }

    if (tid < 128) out[r * H_N + h] = sbuf[par][h];
}

extern "C" void kernel_launch(void* const* d_in, const int* in_sizes, int n_in,
                              void* d_out, int out_size, void* d_ws, size_t ws_size,
                              hipStream_t stream) {
    const float* x    = (const float*)d_in[0];  // [B][T][D] fp32
    const float* w    = (const float*)d_in[1];  // [D][H]    fp32
    const float* wst  = (const float*)d_in[2];  // [H][H]    fp32
    const float* bias = (const float*)d_in[3];  // [H]       fp32
    float* out = (float*)d_out;                 // [B][H]    fp32

    k_fused<<<256, 256, 0, stream>>>(x, w, wst, bias, out);
}